// Round 19
// baseline (1108.726 us; speedup 1.0000x reference)
//
#include <hip/hip_runtime.h>
#include <hip/hip_bf16.h>
#include <math.h>

// PaiNN forward, MI355X. Round 19 (base = round 18):
//  - msg_kernel: depth-2 software pipeline. Prefetch edge q+1's metadata
//    (srcs/geoms) AND its 2x12B sv gathers BEFORE computing edge q's
//    RBF+accumulate -> q+1's memory latency hides under q's VALU work.
//    Clamped prefetch index (no divergent guard). ~+13 VGPR, no shfl.
//    Math order identical -> absmax must stay 0.00390625.
// Everything else identical to round 18.

#define N_NODES 40000
#define N_EDGES 400000
#define NGAUSS  50
#define NLAY    3
#define NGRAPH  256

#define WS_BYTES (448ull * 1024 * 1024)
__device__ __align__(256) unsigned char g_ws[WS_BYTES];

typedef __attribute__((ext_vector_type(8))) short short8;
typedef __attribute__((ext_vector_type(4))) float f32x4;

__device__ __forceinline__ float relu_f(float x) { return fmaxf(x, 0.f); }
__device__ __forceinline__ unsigned short f2b(float x) {
  __hip_bfloat16 h = __float2bfloat16(x);
  return *reinterpret_cast<unsigned short*>(&h);
}
__device__ __forceinline__ float b2f(unsigned short u) {
  return __uint_as_float(((unsigned int)u) << 16);
}
__device__ __forceinline__ float b2f_lo(unsigned int u) {
  return __uint_as_float(u << 16);
}
__device__ __forceinline__ float b2f_hi(unsigned int u) {
  return __uint_as_float(u & 0xffff0000u);
}
__device__ __forceinline__ unsigned int pk(float a, float b) {
  return (unsigned int)f2b(a) | ((unsigned int)f2b(b) << 16);
}
__device__ __forceinline__ int perm384(int c) {   // msg interleave permutation
  int j = c >> 7, cc = c & 127;
  return (cc >> 1) * 6 + j * 2 + (cc & 1);
}

// ---------- fused weight conversion (one launch) ----------
#define S0 (NLAY * 128 * 128)     // m1
#define S1 (NLAY * 128 * 384)     // m2 (col-permuted)
#define S2 (NLAY * 128 * 256)     // vw
#define S3 (NLAY * 256 * 128)     // u1
#define S4 (NLAY * 128 * 384)     // u2
#define S5 (NLAY * NGAUSS * 384)  // fw (interleaved)
#define S6 (128 * 64)             // ro
#define S7 (NLAY * 384)           // mb2 permuted (f32)
#define S_TOT (S0 + S1 + S2 + S3 + S4 + S5 + S6 + S7)

__global__ __launch_bounds__(256) void cvt_all_kernel(
    const float* __restrict__ m1i, const float* __restrict__ m2i,
    const float* __restrict__ vwi, const float* __restrict__ u1i,
    const float* __restrict__ u2i, const float* __restrict__ fwi,
    const float* __restrict__ roi, const float* __restrict__ mb2i,
    unsigned short* __restrict__ m1o, unsigned short* __restrict__ m2o,
    unsigned short* __restrict__ vwo, unsigned short* __restrict__ u1o,
    unsigned short* __restrict__ u2o, unsigned short* __restrict__ fwo,
    unsigned short* __restrict__ roo, float* __restrict__ mb2o) {
  int i = blockIdx.x * 256 + threadIdx.x;
  if (i >= S_TOT) return;
  if (i < S0) { m1o[i] = f2b(m1i[i]); return; }
  i -= S0;
  if (i < S1) {
    int l = i / (128 * 384), rem = i % (128 * 384);
    int r = rem / 384, c = rem % 384;
    m2o[(size_t)l * 128 * 384 + r * 384 + perm384(c)] = f2b(m2i[i]);
    return;
  }
  i -= S1;
  if (i < S2) { vwo[i] = f2b(vwi[i]); return; }
  i -= S2;
  if (i < S3) { u1o[i] = f2b(u1i[i]); return; }
  i -= S3;
  if (i < S4) { u2o[i] = f2b(u2i[i]); return; }
  i -= S4;
  if (i < S5) {
    int l = i / (NGAUSS * 384), rem = i % (NGAUSS * 384);
    int g = rem / 384, c = rem % 384;
    fwo[(size_t)l * NGAUSS * 384 + g * 384 + perm384(c)] = f2b(fwi[i]);
    return;
  }
  i -= S5;
  if (i < S6) { roo[i] = f2b(roi[i]); return; }
  i -= S6;
  {
    int l = i / 384, c = i % 384;
    mb2o[l * 384 + perm384(c)] = mb2i[i];
  }
}

// ---------- CSR build ----------
__global__ __launch_bounds__(256) void hist_kernel(const int* __restrict__ dst,
                                                   int* __restrict__ deg) {
  int e = blockIdx.x * 256 + threadIdx.x;
  if (e < N_EDGES) atomicAdd(&deg[dst[e]], 1);
}

#define SCAN_NB ((N_NODES + 255) / 256)   // 157
__global__ __launch_bounds__(256) void scan_a(const int* __restrict__ deg,
                                              int* __restrict__ bsum) {
  __shared__ int red[4];
  int b = blockIdx.x, t = threadIdx.x;
  int i = b * 256 + t;
  int x = (i < N_NODES) ? deg[i] : 0;
#pragma unroll
  for (int o = 32; o > 0; o >>= 1) x += __shfl_xor(x, o);
  if ((t & 63) == 0) red[t >> 6] = x;
  __syncthreads();
  if (t == 0) bsum[b] = red[0] + red[1] + red[2] + red[3];
}

__global__ __launch_bounds__(64) void scan_b(const int* __restrict__ bsum,
                                             int* __restrict__ boff) {
  int lane = threadIdx.x;
  int carry = 0;
  for (int base = 0; base < SCAN_NB; base += 64) {
    int i = base + lane;
    int v = (i < SCAN_NB) ? bsum[i] : 0;
    int x = v;
#pragma unroll
    for (int d = 1; d < 64; d <<= 1) {
      int y = __shfl_up(x, d);
      if (lane >= d) x += y;
    }
    if (i < SCAN_NB) boff[i] = carry + x - v;
    carry += __shfl(x, 63);
  }
}

__global__ __launch_bounds__(256) void scan_c(const int* __restrict__ deg,
                                              const int* __restrict__ boff,
                                              int* __restrict__ off) {
  __shared__ int woff[4];
  int b = blockIdx.x, t = threadIdx.x, lane = t & 63, w = t >> 6;
  int i = b * 256 + t;
  int v = (i < N_NODES) ? deg[i] : 0;
  int x = v;
#pragma unroll
  for (int d = 1; d < 64; d <<= 1) {
    int y = __shfl_up(x, d);
    if (lane >= d) x += y;
  }
  if (lane == 63) woff[w] = x;
  __syncthreads();
  int add = 0;
  for (int k = 0; k < w; ++k) add += woff[k];
  if (i < N_NODES) off[i] = boff[b] + add + x - v;
  if (b == 0 && t == 0) off[N_NODES] = N_EDGES;
}

// fill: compute geometry AND scatter src/geom into CSR slot order (fused)
__global__ __launch_bounds__(256) void fill_kernel(const int* __restrict__ src,
                                                   const int* __restrict__ dst,
                                                   const int* __restrict__ off,
                                                   int* __restrict__ cursor,
                                                   const float* __restrict__ pos,
                                                   int* __restrict__ srcs,
                                                   float4* __restrict__ geoms) {
  int e = blockIdx.x * 256 + threadIdx.x;
  if (e >= N_EDGES) return;
  int s = src[e], d = dst[e];
  float dx = pos[s * 3 + 0] - pos[d * 3 + 0];
  float dy = pos[s * 3 + 1] - pos[d * 3 + 1];
  float dz = pos[s * 3 + 2] - pos[d * 3 + 2];
  float dist = sqrtf(dx * dx + dy * dy + dz * dz);
  float inv = 1.f / (dist + 1e-8f);
  int p = atomicAdd(&cursor[d], 1);
  int q = off[d] + p;
  srcs[q] = s;
  geoms[q] = make_float4(dx * inv, dy * inv, dz * inv, dist);
}

// ---------- init: s = embed[z] (f32 + bf16), sv v-half = 0 ----------
__global__ __launch_bounds__(256) void init_kernel(const int* __restrict__ z,
                                                   const float* __restrict__ embed,
                                                   float* __restrict__ s,
                                                   unsigned short* __restrict__ sb,
                                                   unsigned short* __restrict__ sv) {
  int idx = blockIdx.x * 256 + threadIdx.x;
  if (idx < N_NODES * 384) {
    int node = idx / 384, c = idx % 384;
    sv[(size_t)node * 768 + 384 + c] = 0;
  }
  if (idx < N_NODES * 128) {
    int node = idx >> 7, c = idx & 127;
    float val = embed[z[node] * 128 + c];
    s[idx] = val;
    sb[idx] = f2b(val);
  }
}

// ---------- bf16 MFMA GEMM: BM=128, BN/KT templated, 4 waves ----------
// outMode: 0 = f32 store, 1 = bf16 row-major store. Requires K <= KT.
template <int BN, int KT>
__global__ __launch_bounds__(256) void gemm_bf16(
    const unsigned short* __restrict__ A1, int lda1,
    const unsigned short* __restrict__ A2, int lda2, int kSplit,
    const unsigned short* __restrict__ B, int ldb,
    const float* __restrict__ bias,
    void* __restrict__ C, int ldc, int M, int K, int doRelu, int outMode) {
  constexpr int NF = BN / 16;
  constexpr int CT = BN / 4;
  __shared__ unsigned int Bt32[BN][KT / 2 + 4];
  int t = threadIdx.x;
  int lane = t & 63, w = t >> 6;
  int n0 = blockIdx.x * BN, m0 = blockIdx.y * 128;
  {
    int c4 = (t & (CT - 1)) * 4;
    int kstep = 2 * (256 / CT);
    for (int k = (t / CT) * 2; k < K; k += kstep) {
      uint2 va = *(const uint2*)&B[(size_t)k * ldb + n0 + c4];
      uint2 vb = *(const uint2*)&B[(size_t)(k + 1) * ldb + n0 + c4];
      Bt32[c4 + 0][k >> 1] = (va.x & 0xffffu) | (vb.x << 16);
      Bt32[c4 + 1][k >> 1] = (va.x >> 16) | (vb.x & 0xffff0000u);
      Bt32[c4 + 2][k >> 1] = (va.y & 0xffffu) | (vb.y << 16);
      Bt32[c4 + 3][k >> 1] = (va.y >> 16) | (vb.y & 0xffff0000u);
    }
  }
  __syncthreads();

  int row = lane & 15;
  int kg = lane >> 4;

  f32x4 acc[2][NF];
#pragma unroll
  for (int rf = 0; rf < 2; ++rf)
#pragma unroll
    for (int nf = 0; nf < NF; ++nf) acc[rf][nf] = (f32x4){0.f, 0.f, 0.f, 0.f};

  for (int ks = 0; ks < K; ks += 32) {
    int kk = ks + kg * 8;
    short8 af[2];
#pragma unroll
    for (int rf = 0; rf < 2; ++rf) {
      int mrow = m0 + w * 32 + rf * 16 + row;
      if (mrow >= M) mrow = M - 1;
      const unsigned short* Ap;
      int kloc;
      if (kk < kSplit) { Ap = A1 + (size_t)mrow * lda1; kloc = kk; }
      else             { Ap = A2 + (size_t)mrow * lda2; kloc = kk - kSplit; }
      af[rf] = *(const short8*)&Ap[kloc];
    }
#pragma unroll
    for (int nf = 0; nf < NF; ++nf) {
      short8 bf = *(const short8*)((const unsigned short*)Bt32[nf * 16 + row] + kk);
#pragma unroll
      for (int rf = 0; rf < 2; ++rf)
        acc[rf][nf] = __builtin_amdgcn_mfma_f32_16x16x32_bf16(af[rf], bf,
                                                              acc[rf][nf], 0, 0, 0);
    }
  }

#pragma unroll
  for (int rf = 0; rf < 2; ++rf)
#pragma unroll
    for (int nf = 0; nf < NF; ++nf)
#pragma unroll
      for (int r = 0; r < 4; ++r) {
        int gr = m0 + w * 32 + rf * 16 + kg * 4 + r;
        int gc = n0 + nf * 16 + row;
        if (gr < M) {
          float val = acc[rf][nf][r] + (bias ? bias[gc] : 0.f);
          if (doRelu) val = relu_f(val);
          if (outMode == 0) ((float*)C)[(size_t)gr * ldc + gc] = val;
          else              ((unsigned short*)C)[(size_t)gr * ldc + gc] = f2b(val);
        }
      }
}

// ---------- fused edge message: depth-2 software pipeline ----------
// sv row per node: uints [0..191] = s interleaved, [192..383] = v interleaved.
__global__ __launch_bounds__(256) void msg_kernel(const int* __restrict__ off,
                                                  const int* __restrict__ srcs,
                                                  const float4* __restrict__ geoms,
                                                  const unsigned int* __restrict__ sv,
                                                  const unsigned int* __restrict__ fwX,
                                                  const float* __restrict__ fb,
                                                  const float* __restrict__ s_in,
                                                  float* __restrict__ s_out,
                                                  unsigned short* __restrict__ s_out_b,
                                                  unsigned short* __restrict__ v_out_b) {
  int node = blockIdx.x * 4 + (threadIdx.x >> 6);
  if (node >= N_NODES) return;
  int lane = threadIdx.x & 63;
  int c2 = lane * 2;
  const float DELTA = 6.0f / 49.0f;
  const float INVD = 49.0f / 6.0f;
  const float CO = -0.5f * INVD * INVD;
  float fbr[3][2];
#pragma unroll
  for (int jj = 0; jj < 3; ++jj) {
    float2 f = *(const float2*)&fb[jj * 128 + c2];
    fbr[jj][0] = f.x; fbr[jj][1] = f.y;
  }
  float ds[2] = {0.f, 0.f};
  float dv[3][2] = {{0.f}};
  int e0 = off[node], e1 = off[node + 1];

  // prefetch edge e0 (clamped: harmless dummy when degree==0)
  int qp = (e0 < e1) ? e0 : 0;
  float4 gm_n = geoms[qp];
  const unsigned int* base_n = sv + (size_t)srcs[qp] * 384 + lane * 3;
  unsigned int s0n = base_n[0], s1n = base_n[1], s2n = base_n[2];
  unsigned int v0n = base_n[192], v1n = base_n[193], v2n = base_n[194];

  for (int q = e0; q < e1; ++q) {
    // consume prefetched edge q
    float4 gm = gm_n;
    unsigned int s0 = s0n, s1 = s1n, s2 = s2n;
    unsigned int v0 = v0n, v1 = v1n, v2 = v2n;
    // issue prefetch for edge q+1 (clamped; dead on last iteration)
    int qn = (q + 1 < e1) ? (q + 1) : q;
    gm_n = geoms[qn];
    base_n = sv + (size_t)srcs[qn] * 384 + lane * 3;
    s0n = base_n[0]; s1n = base_n[1]; s2n = base_n[2];
    v0n = base_n[192]; v1n = base_n[193]; v2n = base_n[194];

    // compute edge q (latency of q+1's loads hides under this)
    float d = gm.w;
    float wv[3][2];
#pragma unroll
    for (int jj = 0; jj < 3; ++jj) { wv[jj][0] = fbr[jj][0]; wv[jj][1] = fbr[jj][1]; }
    int glo = max(0, (int)ceilf(d * INVD - 8.f));
    int ghi = min(NGAUSS - 1, (int)floorf(d * INVD + 8.f));
    for (int g = glo; g <= ghi; ++g) {
      float diff = d - g * DELTA;
      float r = __expf(CO * diff * diff);
      const unsigned int* fr = fwX + g * 192 + lane * 3;
      unsigned int f0 = fr[0], f1 = fr[1], f2v = fr[2];
      wv[0][0] = fmaf(r, b2f_lo(f0), wv[0][0]);
      wv[0][1] = fmaf(r, b2f_hi(f0), wv[0][1]);
      wv[1][0] = fmaf(r, b2f_lo(f1), wv[1][0]);
      wv[1][1] = fmaf(r, b2f_hi(f1), wv[1][1]);
      wv[2][0] = fmaf(r, b2f_lo(f2v), wv[2][0]);
      wv[2][1] = fmaf(r, b2f_hi(f2v), wv[2][1]);
    }
    float gt[3][2];
    gt[0][0] = b2f_lo(s0) * wv[0][0];
    gt[0][1] = b2f_hi(s0) * wv[0][1];
    gt[1][0] = b2f_lo(s1) * wv[1][0];
    gt[1][1] = b2f_hi(s1) * wv[1][1];
    gt[2][0] = b2f_lo(s2) * wv[2][0];
    gt[2][1] = b2f_hi(s2) * wv[2][1];
    ds[0] += gt[0][0];
    ds[1] += gt[0][1];
    float dn[3] = {gm.x, gm.y, gm.z};
    unsigned int vvs[3] = {v0, v1, v2};
#pragma unroll
    for (int dd = 0; dd < 3; ++dd) {
      dv[dd][0] = fmaf(b2f_lo(vvs[dd]), gt[1][0], fmaf(dn[dd], gt[2][0], dv[dd][0]));
      dv[dd][1] = fmaf(b2f_hi(vvs[dd]), gt[1][1], fmaf(dn[dd], gt[2][1], dv[dd][1]));
    }
  }

  size_t sb = (size_t)node * 128 + c2;
  float2 si = *(const float2*)&s_in[sb];
  float2 so = make_float2(si.x + ds[0], si.y + ds[1]);
  *(float2*)&s_out[sb] = so;
  *(unsigned int*)&s_out_b[sb] = pk(so.x, so.y);
  const unsigned int* pv0 = sv + (size_t)node * 384 + 192 + lane * 3;
  unsigned int vi0 = pv0[0], vi1 = pv0[1], vi2 = pv0[2];
  unsigned int vis[3] = {vi0, vi1, vi2};
#pragma unroll
  for (int dd = 0; dd < 3; ++dd) {
    size_t vb = (size_t)node * 384 + dd * 128 + c2;
    float vo0 = b2f_lo(vis[dd]) + dv[dd][0];
    float vo1 = b2f_hi(vis[dd]) + dv[dd][1];
    *(unsigned int*)&v_out_b[vb] = pk(vo0, vo1);
  }
}

// ---------- v_norm from bf16 V buffer [N*3,256] (V1 = cols 0..127) ----------
__global__ __launch_bounds__(256) void vnorm_kernel(const unsigned short* __restrict__ V12b,
                                                    unsigned short* __restrict__ vnb) {
  int idx = blockIdx.x * 256 + threadIdx.x;   // over N_NODES*32
  if (idx >= N_NODES * 32) return;
  int node = idx >> 5, c4 = (idx & 31) * 4;
  size_t b = (size_t)node * 768 + c4;
  ushort4 x = *(const ushort4*)&V12b[b];
  ushort4 y = *(const ushort4*)&V12b[b + 256];
  ushort4 zz = *(const ushort4*)&V12b[b + 512];
  ushort4 o;
  o.x = f2b(sqrtf(b2f(x.x) * b2f(x.x) + b2f(y.x) * b2f(y.x) + b2f(zz.x) * b2f(zz.x)));
  o.y = f2b(sqrtf(b2f(x.y) * b2f(x.y) + b2f(y.y) * b2f(y.y) + b2f(zz.y) * b2f(zz.y)));
  o.z = f2b(sqrtf(b2f(x.z) * b2f(x.z) + b2f(y.z) * b2f(y.z) + b2f(zz.z) * b2f(zz.z)));
  o.w = f2b(sqrtf(b2f(x.w) * b2f(x.w) + b2f(y.w) * b2f(y.w) + b2f(zz.w) * b2f(zz.w)));
  *(ushort4*)&vnb[(size_t)node * 128 + c4] = o;
}

// ---------- per-layer update: s += a ; v = v*b + V2*c (v -> sv v-half) ----------
__global__ __launch_bounds__(256) void update_kernel(const float* __restrict__ s_msg,
                                                     const unsigned short* __restrict__ v_msg_b,
                                                     const unsigned short* __restrict__ u_b,
                                                     const unsigned short* __restrict__ V12b,
                                                     float* __restrict__ s_out,
                                                     unsigned short* __restrict__ s_out_b,
                                                     unsigned int* __restrict__ sv) {
  int idx = blockIdx.x * 256 + threadIdx.x;   // over N_NODES*32
  if (idx >= N_NODES * 32) return;
  int node = idx >> 5, c4 = (idx & 31) * 4;
  size_t ub = (size_t)node * 384 + c4;
  ushort4 a4 = *(const ushort4*)&u_b[ub];
  ushort4 b4 = *(const ushort4*)&u_b[ub + 128];
  ushort4 c4v = *(const ushort4*)&u_b[ub + 256];
  size_t sb = (size_t)node * 128 + c4;
  float4 sm = *(const float4*)&s_msg[sb];
  float4 so = make_float4(sm.x + b2f(a4.x), sm.y + b2f(a4.y),
                          sm.z + b2f(a4.z), sm.w + b2f(a4.w));
  *(float4*)&s_out[sb] = so;
  ushort4 sob = {f2b(so.x), f2b(so.y), f2b(so.z), f2b(so.w)};
  *(ushort4*)&s_out_b[sb] = sob;
  float bb[4] = {b2f(b4.x), b2f(b4.y), b2f(b4.z), b2f(b4.w)};
  float cc[4] = {b2f(c4v.x), b2f(c4v.y), b2f(c4v.z), b2f(c4v.w)};
  int l0 = c4 >> 1;
#pragma unroll
  for (int dd = 0; dd < 3; ++dd) {
    size_t vb = (size_t)node * 384 + dd * 128 + c4;
    size_t vbv = (size_t)node * 768 + dd * 256 + 128 + c4;
    ushort4 vm = *(const ushort4*)&v_msg_b[vb];
    ushort4 v2 = *(const ushort4*)&V12b[vbv];
    float o0 = b2f(vm.x) * bb[0] + b2f(v2.x) * cc[0];
    float o1 = b2f(vm.y) * bb[1] + b2f(v2.y) * cc[1];
    float o2 = b2f(vm.z) * bb[2] + b2f(v2.z) * cc[2];
    float o3 = b2f(vm.w) * bb[3] + b2f(v2.w) * cc[3];
    sv[(size_t)node * 384 + 192 + l0 * 3 + dd] = pk(o0, o1);
    sv[(size_t)node * 384 + 192 + (l0 + 1) * 3 + dd] = pk(o2, o3);
  }
}

// ---------- readout part 2: y[node] = relu_h . w2 (no atomics) ----------
__global__ __launch_bounds__(256) void readout2_kernel(const float* __restrict__ ro_h,
                                                       const float* __restrict__ w2,
                                                       float* __restrict__ y) {
  int node = blockIdx.x * 4 + (threadIdx.x >> 6);
  if (node >= N_NODES) return;
  int lane = threadIdx.x & 63;
  float v = ro_h[(size_t)node * 64 + lane] * w2[lane];
#pragma unroll
  for (int o = 32; o > 0; o >>= 1) v += __shfl_xor(v, o);
  if (lane == 0) y[node] = v;
}

// ---------- pooled mean per graph: wave per graph, binary search range ----------
__global__ __launch_bounds__(64) void pool_kernel(const float* __restrict__ y,
                                                  const int* __restrict__ batch,
                                                  const float* __restrict__ b2,
                                                  float* __restrict__ out) {
  int g = blockIdx.x;
  int lane = threadIdx.x;
  int s, e;
  {
    int lo = 0, hi = N_NODES;
    while (lo < hi) { int mid = (lo + hi) >> 1; if (batch[mid] < g) lo = mid + 1; else hi = mid; }
    s = lo;
    lo = s; hi = N_NODES;
    while (lo < hi) { int mid = (lo + hi) >> 1; if (batch[mid] < g + 1) lo = mid + 1; else hi = mid; }
    e = lo;
  }
  float acc = 0.f;
  for (int i = s + lane; i < e; i += 64) acc += y[i];
#pragma unroll
  for (int o = 32; o > 0; o >>= 1) acc += __shfl_xor(acc, o);
  if (lane == 0) {
    float c = (float)(e - s);
    out[g] = (acc + c * b2[0]) / fmaxf(c, 1.f);
  }
}

// ---------- host ----------
extern "C" void kernel_launch(void* const* d_in, const int* in_sizes, int n_in,
                              void* d_out, int out_size, void* d_ws, size_t ws_size,
                              hipStream_t stream) {
  const int*   z      = (const int*)d_in[0];
  const float* pos    = (const float*)d_in[1];
  const int*   esrc   = (const int*)d_in[2];
  const int*   edst   = esrc + N_EDGES;
  const int*   batch  = (const int*)d_in[3];
  const float* embed  = (const float*)d_in[4];
  const float* msg_w1 = (const float*)d_in[5];
  const float* msg_b1 = (const float*)d_in[6];
  const float* msg_w2 = (const float*)d_in[7];
  const float* msg_b2 = (const float*)d_in[8];
  const float* filt_w = (const float*)d_in[9];
  const float* filt_b = (const float*)d_in[10];
  const float* vec_w  = (const float*)d_in[11];
  const float* upd_w1 = (const float*)d_in[12];
  const float* upd_b1 = (const float*)d_in[13];
  const float* upd_w2 = (const float*)d_in[14];
  const float* upd_b2 = (const float*)d_in[15];
  const float* ro_w1  = (const float*)d_in[16];
  const float* ro_b1  = (const float*)d_in[17];
  const float* ro_w2  = (const float*)d_in[18];
  const float* ro_b2  = (const float*)d_in[19];
  (void)in_sizes; (void)n_in; (void)out_size;

  void* wsp = nullptr;
  if (hipGetSymbolAddress(&wsp, HIP_SYMBOL(g_ws)) != hipSuccess || wsp == nullptr) {
    wsp = d_ws;
  }
  char* wsb = (char*)wsp;
  size_t o = 0;
  auto alloc = [&](size_t bytes) -> void* {
    void* p = wsb + o;
    o += (bytes + 255) & ~(size_t)255;
    return p;
  };
  float4* geoms  = (float4*)alloc(sizeof(float4) * N_EDGES);   // CSR order
  int* srcs      = (int*)alloc(4ull * N_EDGES);                // CSR order
  int* csr_off   = (int*)alloc(4ull * (N_NODES + 1));
  int* deg       = (int*)alloc(4ull * N_NODES);
  int* cursor    = (int*)alloc(4ull * N_NODES);
  int* bsum      = (int*)alloc(4ull * SCAN_NB);
  int* boff      = (int*)alloc(4ull * SCAN_NB);
  float* sA      = (float*)alloc(4ull * N_NODES * 128);
  float* sB      = (float*)alloc(4ull * N_NODES * 128);
  float* ro_h    = (float*)alloc(4ull * N_NODES * 64);
  float* ybuf    = (float*)alloc(4ull * N_NODES);
  float* mb2p    = (float*)alloc(4ull * NLAY * 384);
  unsigned short* svX    = (unsigned short*)alloc(2ull * N_NODES * 768);  // s|v unified
  unsigned short* sAb    = (unsigned short*)alloc(2ull * N_NODES * 128);
  unsigned short* sBb    = (unsigned short*)alloc(2ull * N_NODES * 128);
  unsigned short* vBb    = (unsigned short*)alloc(2ull * N_NODES * 384);
  unsigned short* vnb    = (unsigned short*)alloc(2ull * N_NODES * 128);
  unsigned short* hidden = (unsigned short*)alloc(2ull * N_NODES * 128);
  unsigned short* Vbuf_b = (unsigned short*)alloc(2ull * N_NODES * 768);  // V1|V2
  unsigned short* ubuf_b = (unsigned short*)alloc(2ull * N_NODES * 384);
  unsigned short* wb_m1  = (unsigned short*)alloc(2ull * S0);
  unsigned short* wb_m2  = (unsigned short*)alloc(2ull * S1);   // col-permuted
  unsigned short* wb_vw  = (unsigned short*)alloc(2ull * S2);
  unsigned short* wb_u1  = (unsigned short*)alloc(2ull * S3);
  unsigned short* wb_u2  = (unsigned short*)alloc(2ull * S4);
  unsigned short* wb_fwX = (unsigned short*)alloc(2ull * S5);   // interleaved
  unsigned short* wb_ro  = (unsigned short*)alloc(2ull * S6);

  if (wsb == (char*)d_ws && o > ws_size) return;

  hipMemsetAsync(deg, 0, 4ull * N_NODES, stream);
  hipMemsetAsync(cursor, 0, 4ull * N_NODES, stream);

  cvt_all_kernel<<<(S_TOT + 255) / 256, 256, 0, stream>>>(
      msg_w1, msg_w2, vec_w, upd_w1, upd_w2, filt_w, ro_w1, msg_b2,
      wb_m1, wb_m2, wb_vw, wb_u1, wb_u2, wb_fwX, wb_ro, mb2p);

  hist_kernel<<<(N_EDGES + 255) / 256, 256, 0, stream>>>(edst, deg);
  scan_a<<<SCAN_NB, 256, 0, stream>>>(deg, bsum);
  scan_b<<<1, 64, 0, stream>>>(bsum, boff);
  scan_c<<<SCAN_NB, 256, 0, stream>>>(deg, boff, csr_off);
  fill_kernel<<<(N_EDGES + 255) / 256, 256, 0, stream>>>(esrc, edst, csr_off, cursor,
                                                         pos, srcs, geoms);
  init_kernel<<<(N_NODES * 384 + 255) / 256, 256, 0, stream>>>(z, embed, sA, sAb, svX);

  const int BIG = 1 << 30;
  const int GY40 = (N_NODES + 127) / 128;        // 313
  const int GY120 = (N_NODES * 3 + 127) / 128;   // 938
  for (int i = 0; i < NLAY; ++i) {
    const float* mb1 = msg_b1 + (size_t)i * 128;
    const float* mb2i = mb2p + (size_t)i * 384;   // permuted bias
    const float* fbv = filt_b + (size_t)i * 384;
    const float* ub1 = upd_b1 + (size_t)i * 128;
    const float* ub2 = upd_b2 + (size_t)i * 384;
    const unsigned short* m1 = wb_m1 + (size_t)i * 128 * 128;
    const unsigned short* m2 = wb_m2 + (size_t)i * 128 * 384;
    const unsigned short* vw = wb_vw + (size_t)i * 128 * 256;
    const unsigned short* u1 = wb_u1 + (size_t)i * 256 * 128;
    const unsigned short* u2 = wb_u2 + (size_t)i * 128 * 384;
    const unsigned int* fwX = (const unsigned int*)(wb_fwX + (size_t)i * 50 * 384);

    gemm_bf16<64, 128><<<dim3(2, GY40), 256, 0, stream>>>(sAb, 128, sAb, 128, BIG, m1,
                                                          128, mb1, hidden, 128,
                                                          N_NODES, 128, 1, 1);
    gemm_bf16<128, 128><<<dim3(3, GY40), 256, 0, stream>>>(hidden, 128, hidden, 128,
                                                           BIG, m2, 384, mb2i, svX,
                                                           768, N_NODES, 128, 0, 1);
    msg_kernel<<<N_NODES / 4, 256, 0, stream>>>(csr_off, srcs, geoms,
                                                (const unsigned int*)svX, fwX, fbv,
                                                sA, sB, sBb, vBb);
    gemm_bf16<128, 128><<<dim3(2, GY120), 256, 0, stream>>>(vBb, 128, vBb, 128, BIG,
                                                            vw, 256, nullptr, Vbuf_b,
                                                            256, N_NODES * 3, 128,
                                                            0, 1);
    vnorm_kernel<<<(N_NODES * 32 + 255) / 256, 256, 0, stream>>>(Vbuf_b, vnb);
    gemm_bf16<64, 256><<<dim3(2, GY40), 256, 0, stream>>>(sBb, 128, vnb, 128, 128, u1,
                                                          128, ub1, hidden, 128,
                                                          N_NODES, 256, 1, 1);
    gemm_bf16<128, 128><<<dim3(3, GY40), 256, 0, stream>>>(hidden, 128, hidden, 128,
                                                           BIG, u2, 384, ub2, ubuf_b,
                                                           384, N_NODES, 128, 0, 1);
    update_kernel<<<(N_NODES * 32 + 255) / 256, 256, 0, stream>>>(sB, vBb, ubuf_b,
                                                                  Vbuf_b, sA, sAb,
                                                                  (unsigned int*)svX);
  }

  gemm_bf16<64, 128><<<dim3(1, GY40), 256, 0, stream>>>(sAb, 128, sAb, 128, BIG, wb_ro,
                                                        64, ro_b1, ro_h, 64, N_NODES,
                                                        128, 1, 0);
  readout2_kernel<<<N_NODES / 4, 256, 0, stream>>>(ro_h, ro_w2, ybuf);
  pool_kernel<<<NGRAPH, 64, 0, stream>>>(ybuf, batch, ro_b2, (float*)d_out);
}

// Round 20
// 1086.663 us; speedup vs baseline: 1.0203x; 1.0203x over previous
//
#include <hip/hip_runtime.h>
#include <hip/hip_bf16.h>
#include <math.h>

// PaiNN forward, MI355X. Round 20 = FINAL: revert to round-18 kernel
// (1089us, best verified). Round-19's depth-2 prefetch regressed
// (VGPR 28->36, occ 60->53, msg 136->142) -- same ILP-vs-occupancy trade
// that failed in rounds 6/12. This config is the practical plateau:
// msg at mixed 35% HBM / 44% VALU with five failed restructurings;
// GEMMs at small-K MFMA-density floor; all serial tails eliminated.

#define N_NODES 40000
#define N_EDGES 400000
#define NGAUSS  50
#define NLAY    3
#define NGRAPH  256

#define WS_BYTES (448ull * 1024 * 1024)
__device__ __align__(256) unsigned char g_ws[WS_BYTES];

typedef __attribute__((ext_vector_type(8))) short short8;
typedef __attribute__((ext_vector_type(4))) float f32x4;

__device__ __forceinline__ float relu_f(float x) { return fmaxf(x, 0.f); }
__device__ __forceinline__ unsigned short f2b(float x) {
  __hip_bfloat16 h = __float2bfloat16(x);
  return *reinterpret_cast<unsigned short*>(&h);
}
__device__ __forceinline__ float b2f(unsigned short u) {
  return __uint_as_float(((unsigned int)u) << 16);
}
__device__ __forceinline__ float b2f_lo(unsigned int u) {
  return __uint_as_float(u << 16);
}
__device__ __forceinline__ float b2f_hi(unsigned int u) {
  return __uint_as_float(u & 0xffff0000u);
}
__device__ __forceinline__ unsigned int pk(float a, float b) {
  return (unsigned int)f2b(a) | ((unsigned int)f2b(b) << 16);
}
__device__ __forceinline__ int perm384(int c) {   // msg interleave permutation
  int j = c >> 7, cc = c & 127;
  return (cc >> 1) * 6 + j * 2 + (cc & 1);
}

// ---------- fused weight conversion (one launch) ----------
#define S0 (NLAY * 128 * 128)     // m1
#define S1 (NLAY * 128 * 384)     // m2 (col-permuted)
#define S2 (NLAY * 128 * 256)     // vw
#define S3 (NLAY * 256 * 128)     // u1
#define S4 (NLAY * 128 * 384)     // u2
#define S5 (NLAY * NGAUSS * 384)  // fw (interleaved)
#define S6 (128 * 64)             // ro
#define S7 (NLAY * 384)           // mb2 permuted (f32)
#define S_TOT (S0 + S1 + S2 + S3 + S4 + S5 + S6 + S7)

__global__ __launch_bounds__(256) void cvt_all_kernel(
    const float* __restrict__ m1i, const float* __restrict__ m2i,
    const float* __restrict__ vwi, const float* __restrict__ u1i,
    const float* __restrict__ u2i, const float* __restrict__ fwi,
    const float* __restrict__ roi, const float* __restrict__ mb2i,
    unsigned short* __restrict__ m1o, unsigned short* __restrict__ m2o,
    unsigned short* __restrict__ vwo, unsigned short* __restrict__ u1o,
    unsigned short* __restrict__ u2o, unsigned short* __restrict__ fwo,
    unsigned short* __restrict__ roo, float* __restrict__ mb2o) {
  int i = blockIdx.x * 256 + threadIdx.x;
  if (i >= S_TOT) return;
  if (i < S0) { m1o[i] = f2b(m1i[i]); return; }
  i -= S0;
  if (i < S1) {
    int l = i / (128 * 384), rem = i % (128 * 384);
    int r = rem / 384, c = rem % 384;
    m2o[(size_t)l * 128 * 384 + r * 384 + perm384(c)] = f2b(m2i[i]);
    return;
  }
  i -= S1;
  if (i < S2) { vwo[i] = f2b(vwi[i]); return; }
  i -= S2;
  if (i < S3) { u1o[i] = f2b(u1i[i]); return; }
  i -= S3;
  if (i < S4) { u2o[i] = f2b(u2i[i]); return; }
  i -= S4;
  if (i < S5) {
    int l = i / (NGAUSS * 384), rem = i % (NGAUSS * 384);
    int g = rem / 384, c = rem % 384;
    fwo[(size_t)l * NGAUSS * 384 + g * 384 + perm384(c)] = f2b(fwi[i]);
    return;
  }
  i -= S5;
  if (i < S6) { roo[i] = f2b(roi[i]); return; }
  i -= S6;
  {
    int l = i / 384, c = i % 384;
    mb2o[l * 384 + perm384(c)] = mb2i[i];
  }
}

// ---------- CSR build ----------
__global__ __launch_bounds__(256) void hist_kernel(const int* __restrict__ dst,
                                                   int* __restrict__ deg) {
  int e = blockIdx.x * 256 + threadIdx.x;
  if (e < N_EDGES) atomicAdd(&deg[dst[e]], 1);
}

#define SCAN_NB ((N_NODES + 255) / 256)   // 157
__global__ __launch_bounds__(256) void scan_a(const int* __restrict__ deg,
                                              int* __restrict__ bsum) {
  __shared__ int red[4];
  int b = blockIdx.x, t = threadIdx.x;
  int i = b * 256 + t;
  int x = (i < N_NODES) ? deg[i] : 0;
#pragma unroll
  for (int o = 32; o > 0; o >>= 1) x += __shfl_xor(x, o);
  if ((t & 63) == 0) red[t >> 6] = x;
  __syncthreads();
  if (t == 0) bsum[b] = red[0] + red[1] + red[2] + red[3];
}

__global__ __launch_bounds__(64) void scan_b(const int* __restrict__ bsum,
                                             int* __restrict__ boff) {
  int lane = threadIdx.x;
  int carry = 0;
  for (int base = 0; base < SCAN_NB; base += 64) {
    int i = base + lane;
    int v = (i < SCAN_NB) ? bsum[i] : 0;
    int x = v;
#pragma unroll
    for (int d = 1; d < 64; d <<= 1) {
      int y = __shfl_up(x, d);
      if (lane >= d) x += y;
    }
    if (i < SCAN_NB) boff[i] = carry + x - v;
    carry += __shfl(x, 63);
  }
}

__global__ __launch_bounds__(256) void scan_c(const int* __restrict__ deg,
                                              const int* __restrict__ boff,
                                              int* __restrict__ off) {
  __shared__ int woff[4];
  int b = blockIdx.x, t = threadIdx.x, lane = t & 63, w = t >> 6;
  int i = b * 256 + t;
  int v = (i < N_NODES) ? deg[i] : 0;
  int x = v;
#pragma unroll
  for (int d = 1; d < 64; d <<= 1) {
    int y = __shfl_up(x, d);
    if (lane >= d) x += y;
  }
  if (lane == 63) woff[w] = x;
  __syncthreads();
  int add = 0;
  for (int k = 0; k < w; ++k) add += woff[k];
  if (i < N_NODES) off[i] = boff[b] + add + x - v;
  if (b == 0 && t == 0) off[N_NODES] = N_EDGES;
}

// fill: compute geometry AND scatter src/geom into CSR slot order (fused)
__global__ __launch_bounds__(256) void fill_kernel(const int* __restrict__ src,
                                                   const int* __restrict__ dst,
                                                   const int* __restrict__ off,
                                                   int* __restrict__ cursor,
                                                   const float* __restrict__ pos,
                                                   int* __restrict__ srcs,
                                                   float4* __restrict__ geoms) {
  int e = blockIdx.x * 256 + threadIdx.x;
  if (e >= N_EDGES) return;
  int s = src[e], d = dst[e];
  float dx = pos[s * 3 + 0] - pos[d * 3 + 0];
  float dy = pos[s * 3 + 1] - pos[d * 3 + 1];
  float dz = pos[s * 3 + 2] - pos[d * 3 + 2];
  float dist = sqrtf(dx * dx + dy * dy + dz * dz);
  float inv = 1.f / (dist + 1e-8f);
  int p = atomicAdd(&cursor[d], 1);
  int q = off[d] + p;
  srcs[q] = s;
  geoms[q] = make_float4(dx * inv, dy * inv, dz * inv, dist);
}

// ---------- init: s = embed[z] (f32 + bf16), sv v-half = 0 ----------
__global__ __launch_bounds__(256) void init_kernel(const int* __restrict__ z,
                                                   const float* __restrict__ embed,
                                                   float* __restrict__ s,
                                                   unsigned short* __restrict__ sb,
                                                   unsigned short* __restrict__ sv) {
  int idx = blockIdx.x * 256 + threadIdx.x;
  if (idx < N_NODES * 384) {
    int node = idx / 384, c = idx % 384;
    sv[(size_t)node * 768 + 384 + c] = 0;
  }
  if (idx < N_NODES * 128) {
    int node = idx >> 7, c = idx & 127;
    float val = embed[z[node] * 128 + c];
    s[idx] = val;
    sb[idx] = f2b(val);
  }
}

// ---------- bf16 MFMA GEMM: BM=128, BN/KT templated, 4 waves ----------
// outMode: 0 = f32 store, 1 = bf16 row-major store. Requires K <= KT.
template <int BN, int KT>
__global__ __launch_bounds__(256) void gemm_bf16(
    const unsigned short* __restrict__ A1, int lda1,
    const unsigned short* __restrict__ A2, int lda2, int kSplit,
    const unsigned short* __restrict__ B, int ldb,
    const float* __restrict__ bias,
    void* __restrict__ C, int ldc, int M, int K, int doRelu, int outMode) {
  constexpr int NF = BN / 16;
  constexpr int CT = BN / 4;
  __shared__ unsigned int Bt32[BN][KT / 2 + 4];
  int t = threadIdx.x;
  int lane = t & 63, w = t >> 6;
  int n0 = blockIdx.x * BN, m0 = blockIdx.y * 128;
  {
    int c4 = (t & (CT - 1)) * 4;
    int kstep = 2 * (256 / CT);
    for (int k = (t / CT) * 2; k < K; k += kstep) {
      uint2 va = *(const uint2*)&B[(size_t)k * ldb + n0 + c4];
      uint2 vb = *(const uint2*)&B[(size_t)(k + 1) * ldb + n0 + c4];
      Bt32[c4 + 0][k >> 1] = (va.x & 0xffffu) | (vb.x << 16);
      Bt32[c4 + 1][k >> 1] = (va.x >> 16) | (vb.x & 0xffff0000u);
      Bt32[c4 + 2][k >> 1] = (va.y & 0xffffu) | (vb.y << 16);
      Bt32[c4 + 3][k >> 1] = (va.y >> 16) | (vb.y & 0xffff0000u);
    }
  }
  __syncthreads();

  int row = lane & 15;
  int kg = lane >> 4;

  f32x4 acc[2][NF];
#pragma unroll
  for (int rf = 0; rf < 2; ++rf)
#pragma unroll
    for (int nf = 0; nf < NF; ++nf) acc[rf][nf] = (f32x4){0.f, 0.f, 0.f, 0.f};

  for (int ks = 0; ks < K; ks += 32) {
    int kk = ks + kg * 8;
    short8 af[2];
#pragma unroll
    for (int rf = 0; rf < 2; ++rf) {
      int mrow = m0 + w * 32 + rf * 16 + row;
      if (mrow >= M) mrow = M - 1;
      const unsigned short* Ap;
      int kloc;
      if (kk < kSplit) { Ap = A1 + (size_t)mrow * lda1; kloc = kk; }
      else             { Ap = A2 + (size_t)mrow * lda2; kloc = kk - kSplit; }
      af[rf] = *(const short8*)&Ap[kloc];
    }
#pragma unroll
    for (int nf = 0; nf < NF; ++nf) {
      short8 bf = *(const short8*)((const unsigned short*)Bt32[nf * 16 + row] + kk);
#pragma unroll
      for (int rf = 0; rf < 2; ++rf)
        acc[rf][nf] = __builtin_amdgcn_mfma_f32_16x16x32_bf16(af[rf], bf,
                                                              acc[rf][nf], 0, 0, 0);
    }
  }

#pragma unroll
  for (int rf = 0; rf < 2; ++rf)
#pragma unroll
    for (int nf = 0; nf < NF; ++nf)
#pragma unroll
      for (int r = 0; r < 4; ++r) {
        int gr = m0 + w * 32 + rf * 16 + kg * 4 + r;
        int gc = n0 + nf * 16 + row;
        if (gr < M) {
          float val = acc[rf][nf][r] + (bias ? bias[gc] : 0.f);
          if (doRelu) val = relu_f(val);
          if (outMode == 0) ((float*)C)[(size_t)gr * ldc + gc] = val;
          else              ((unsigned short*)C)[(size_t)gr * ldc + gc] = f2b(val);
        }
      }
}

// ---------- fused edge message: unified sv gathers (one base addr) ----------
// sv row per node: uints [0..191] = s interleaved, [192..383] = v interleaved.
__global__ __launch_bounds__(256) void msg_kernel(const int* __restrict__ off,
                                                  const int* __restrict__ srcs,
                                                  const float4* __restrict__ geoms,
                                                  const unsigned int* __restrict__ sv,
                                                  const unsigned int* __restrict__ fwX,
                                                  const float* __restrict__ fb,
                                                  const float* __restrict__ s_in,
                                                  float* __restrict__ s_out,
                                                  unsigned short* __restrict__ s_out_b,
                                                  unsigned short* __restrict__ v_out_b) {
  int node = blockIdx.x * 4 + (threadIdx.x >> 6);
  if (node >= N_NODES) return;
  int lane = threadIdx.x & 63;
  int c2 = lane * 2;
  const float DELTA = 6.0f / 49.0f;
  const float INVD = 49.0f / 6.0f;
  const float CO = -0.5f * INVD * INVD;
  float fbr[3][2];
#pragma unroll
  for (int jj = 0; jj < 3; ++jj) {
    float2 f = *(const float2*)&fb[jj * 128 + c2];
    fbr[jj][0] = f.x; fbr[jj][1] = f.y;
  }
  float ds[2] = {0.f, 0.f};
  float dv[3][2] = {{0.f}};
  int e0 = off[node], e1 = off[node + 1];

  for (int q = e0; q < e1; ++q) {
    int s = srcs[q];
    float4 gm = geoms[q];
    float d = gm.w;
    float wv[3][2];
#pragma unroll
    for (int jj = 0; jj < 3; ++jj) { wv[jj][0] = fbr[jj][0]; wv[jj][1] = fbr[jj][1]; }
    int glo = max(0, (int)ceilf(d * INVD - 8.f));
    int ghi = min(NGAUSS - 1, (int)floorf(d * INVD + 8.f));
    for (int g = glo; g <= ghi; ++g) {
      float diff = d - g * DELTA;
      float r = __expf(CO * diff * diff);
      const unsigned int* fr = fwX + g * 192 + lane * 3;
      unsigned int f0 = fr[0], f1 = fr[1], f2v = fr[2];
      wv[0][0] = fmaf(r, b2f_lo(f0), wv[0][0]);
      wv[0][1] = fmaf(r, b2f_hi(f0), wv[0][1]);
      wv[1][0] = fmaf(r, b2f_lo(f1), wv[1][0]);
      wv[1][1] = fmaf(r, b2f_hi(f1), wv[1][1]);
      wv[2][0] = fmaf(r, b2f_lo(f2v), wv[2][0]);
      wv[2][1] = fmaf(r, b2f_hi(f2v), wv[2][1]);
    }
    const unsigned int* base = sv + (size_t)s * 384 + lane * 3;  // one addr
    unsigned int s0 = base[0], s1 = base[1], s2 = base[2];       // s-half
    unsigned int v0 = base[192], v1 = base[193], v2 = base[194]; // v: +768B imm
    float gt[3][2];
    gt[0][0] = b2f_lo(s0) * wv[0][0];
    gt[0][1] = b2f_hi(s0) * wv[0][1];
    gt[1][0] = b2f_lo(s1) * wv[1][0];
    gt[1][1] = b2f_hi(s1) * wv[1][1];
    gt[2][0] = b2f_lo(s2) * wv[2][0];
    gt[2][1] = b2f_hi(s2) * wv[2][1];
    ds[0] += gt[0][0];
    ds[1] += gt[0][1];
    float dn[3] = {gm.x, gm.y, gm.z};
    unsigned int vvs[3] = {v0, v1, v2};
#pragma unroll
    for (int dd = 0; dd < 3; ++dd) {
      dv[dd][0] = fmaf(b2f_lo(vvs[dd]), gt[1][0], fmaf(dn[dd], gt[2][0], dv[dd][0]));
      dv[dd][1] = fmaf(b2f_hi(vvs[dd]), gt[1][1], fmaf(dn[dd], gt[2][1], dv[dd][1]));
    }
  }

  size_t sb = (size_t)node * 128 + c2;
  float2 si = *(const float2*)&s_in[sb];
  float2 so = make_float2(si.x + ds[0], si.y + ds[1]);
  *(float2*)&s_out[sb] = so;
  *(unsigned int*)&s_out_b[sb] = pk(so.x, so.y);
  const unsigned int* pv0 = sv + (size_t)node * 384 + 192 + lane * 3;
  unsigned int vi0 = pv0[0], vi1 = pv0[1], vi2 = pv0[2];
  unsigned int vis[3] = {vi0, vi1, vi2};
#pragma unroll
  for (int dd = 0; dd < 3; ++dd) {
    size_t vb = (size_t)node * 384 + dd * 128 + c2;
    float vo0 = b2f_lo(vis[dd]) + dv[dd][0];
    float vo1 = b2f_hi(vis[dd]) + dv[dd][1];
    *(unsigned int*)&v_out_b[vb] = pk(vo0, vo1);
  }
}

// ---------- v_norm from bf16 V buffer [N*3,256] (V1 = cols 0..127) ----------
__global__ __launch_bounds__(256) void vnorm_kernel(const unsigned short* __restrict__ V12b,
                                                    unsigned short* __restrict__ vnb) {
  int idx = blockIdx.x * 256 + threadIdx.x;   // over N_NODES*32
  if (idx >= N_NODES * 32) return;
  int node = idx >> 5, c4 = (idx & 31) * 4;
  size_t b = (size_t)node * 768 + c4;
  ushort4 x = *(const ushort4*)&V12b[b];
  ushort4 y = *(const ushort4*)&V12b[b + 256];
  ushort4 zz = *(const ushort4*)&V12b[b + 512];
  ushort4 o;
  o.x = f2b(sqrtf(b2f(x.x) * b2f(x.x) + b2f(y.x) * b2f(y.x) + b2f(zz.x) * b2f(zz.x)));
  o.y = f2b(sqrtf(b2f(x.y) * b2f(x.y) + b2f(y.y) * b2f(y.y) + b2f(zz.y) * b2f(zz.y)));
  o.z = f2b(sqrtf(b2f(x.z) * b2f(x.z) + b2f(y.z) * b2f(y.z) + b2f(zz.z) * b2f(zz.z)));
  o.w = f2b(sqrtf(b2f(x.w) * b2f(x.w) + b2f(y.w) * b2f(y.w) + b2f(zz.w) * b2f(zz.w)));
  *(ushort4*)&vnb[(size_t)node * 128 + c4] = o;
}

// ---------- per-layer update: s += a ; v = v*b + V2*c (v -> sv v-half) ----------
__global__ __launch_bounds__(256) void update_kernel(const float* __restrict__ s_msg,
                                                     const unsigned short* __restrict__ v_msg_b,
                                                     const unsigned short* __restrict__ u_b,
                                                     const unsigned short* __restrict__ V12b,
                                                     float* __restrict__ s_out,
                                                     unsigned short* __restrict__ s_out_b,
                                                     unsigned int* __restrict__ sv) {
  int idx = blockIdx.x * 256 + threadIdx.x;   // over N_NODES*32
  if (idx >= N_NODES * 32) return;
  int node = idx >> 5, c4 = (idx & 31) * 4;
  size_t ub = (size_t)node * 384 + c4;
  ushort4 a4 = *(const ushort4*)&u_b[ub];
  ushort4 b4 = *(const ushort4*)&u_b[ub + 128];
  ushort4 c4v = *(const ushort4*)&u_b[ub + 256];
  size_t sb = (size_t)node * 128 + c4;
  float4 sm = *(const float4*)&s_msg[sb];
  float4 so = make_float4(sm.x + b2f(a4.x), sm.y + b2f(a4.y),
                          sm.z + b2f(a4.z), sm.w + b2f(a4.w));
  *(float4*)&s_out[sb] = so;
  ushort4 sob = {f2b(so.x), f2b(so.y), f2b(so.z), f2b(so.w)};
  *(ushort4*)&s_out_b[sb] = sob;
  float bb[4] = {b2f(b4.x), b2f(b4.y), b2f(b4.z), b2f(b4.w)};
  float cc[4] = {b2f(c4v.x), b2f(c4v.y), b2f(c4v.z), b2f(c4v.w)};
  int l0 = c4 >> 1;
#pragma unroll
  for (int dd = 0; dd < 3; ++dd) {
    size_t vb = (size_t)node * 384 + dd * 128 + c4;
    size_t vbv = (size_t)node * 768 + dd * 256 + 128 + c4;
    ushort4 vm = *(const ushort4*)&v_msg_b[vb];
    ushort4 v2 = *(const ushort4*)&V12b[vbv];
    float o0 = b2f(vm.x) * bb[0] + b2f(v2.x) * cc[0];
    float o1 = b2f(vm.y) * bb[1] + b2f(v2.y) * cc[1];
    float o2 = b2f(vm.z) * bb[2] + b2f(v2.z) * cc[2];
    float o3 = b2f(vm.w) * bb[3] + b2f(v2.w) * cc[3];
    sv[(size_t)node * 384 + 192 + l0 * 3 + dd] = pk(o0, o1);
    sv[(size_t)node * 384 + 192 + (l0 + 1) * 3 + dd] = pk(o2, o3);
  }
}

// ---------- readout part 2: y[node] = relu_h . w2 (no atomics) ----------
__global__ __launch_bounds__(256) void readout2_kernel(const float* __restrict__ ro_h,
                                                       const float* __restrict__ w2,
                                                       float* __restrict__ y) {
  int node = blockIdx.x * 4 + (threadIdx.x >> 6);
  if (node >= N_NODES) return;
  int lane = threadIdx.x & 63;
  float v = ro_h[(size_t)node * 64 + lane] * w2[lane];
#pragma unroll
  for (int o = 32; o > 0; o >>= 1) v += __shfl_xor(v, o);
  if (lane == 0) y[node] = v;
}

// ---------- pooled mean per graph: wave per graph, binary search range ----------
__global__ __launch_bounds__(64) void pool_kernel(const float* __restrict__ y,
                                                  const int* __restrict__ batch,
                                                  const float* __restrict__ b2,
                                                  float* __restrict__ out) {
  int g = blockIdx.x;
  int lane = threadIdx.x;
  int s, e;
  {
    int lo = 0, hi = N_NODES;
    while (lo < hi) { int mid = (lo + hi) >> 1; if (batch[mid] < g) lo = mid + 1; else hi = mid; }
    s = lo;
    lo = s; hi = N_NODES;
    while (lo < hi) { int mid = (lo + hi) >> 1; if (batch[mid] < g + 1) lo = mid + 1; else hi = mid; }
    e = lo;
  }
  float acc = 0.f;
  for (int i = s + lane; i < e; i += 64) acc += y[i];
#pragma unroll
  for (int o = 32; o > 0; o >>= 1) acc += __shfl_xor(acc, o);
  if (lane == 0) {
    float c = (float)(e - s);
    out[g] = (acc + c * b2[0]) / fmaxf(c, 1.f);
  }
}

// ---------- host ----------
extern "C" void kernel_launch(void* const* d_in, const int* in_sizes, int n_in,
                              void* d_out, int out_size, void* d_ws, size_t ws_size,
                              hipStream_t stream) {
  const int*   z      = (const int*)d_in[0];
  const float* pos    = (const float*)d_in[1];
  const int*   esrc   = (const int*)d_in[2];
  const int*   edst   = esrc + N_EDGES;
  const int*   batch  = (const int*)d_in[3];
  const float* embed  = (const float*)d_in[4];
  const float* msg_w1 = (const float*)d_in[5];
  const float* msg_b1 = (const float*)d_in[6];
  const float* msg_w2 = (const float*)d_in[7];
  const float* msg_b2 = (const float*)d_in[8];
  const float* filt_w = (const float*)d_in[9];
  const float* filt_b = (const float*)d_in[10];
  const float* vec_w  = (const float*)d_in[11];
  const float* upd_w1 = (const float*)d_in[12];
  const float* upd_b1 = (const float*)d_in[13];
  const float* upd_w2 = (const float*)d_in[14];
  const float* upd_b2 = (const float*)d_in[15];
  const float* ro_w1  = (const float*)d_in[16];
  const float* ro_b1  = (const float*)d_in[17];
  const float* ro_w2  = (const float*)d_in[18];
  const float* ro_b2  = (const float*)d_in[19];
  (void)in_sizes; (void)n_in; (void)out_size;

  void* wsp = nullptr;
  if (hipGetSymbolAddress(&wsp, HIP_SYMBOL(g_ws)) != hipSuccess || wsp == nullptr) {
    wsp = d_ws;
  }
  char* wsb = (char*)wsp;
  size_t o = 0;
  auto alloc = [&](size_t bytes) -> void* {
    void* p = wsb + o;
    o += (bytes + 255) & ~(size_t)255;
    return p;
  };
  float4* geoms  = (float4*)alloc(sizeof(float4) * N_EDGES);   // CSR order
  int* srcs      = (int*)alloc(4ull * N_EDGES);                // CSR order
  int* csr_off   = (int*)alloc(4ull * (N_NODES + 1));
  int* deg       = (int*)alloc(4ull * N_NODES);
  int* cursor    = (int*)alloc(4ull * N_NODES);
  int* bsum      = (int*)alloc(4ull * SCAN_NB);
  int* boff      = (int*)alloc(4ull * SCAN_NB);
  float* sA      = (float*)alloc(4ull * N_NODES * 128);
  float* sB      = (float*)alloc(4ull * N_NODES * 128);
  float* ro_h    = (float*)alloc(4ull * N_NODES * 64);
  float* ybuf    = (float*)alloc(4ull * N_NODES);
  float* mb2p    = (float*)alloc(4ull * NLAY * 384);
  unsigned short* svX    = (unsigned short*)alloc(2ull * N_NODES * 768);  // s|v unified
  unsigned short* sAb    = (unsigned short*)alloc(2ull * N_NODES * 128);
  unsigned short* sBb    = (unsigned short*)alloc(2ull * N_NODES * 128);
  unsigned short* vBb    = (unsigned short*)alloc(2ull * N_NODES * 384);
  unsigned short* vnb    = (unsigned short*)alloc(2ull * N_NODES * 128);
  unsigned short* hidden = (unsigned short*)alloc(2ull * N_NODES * 128);
  unsigned short* Vbuf_b = (unsigned short*)alloc(2ull * N_NODES * 768);  // V1|V2
  unsigned short* ubuf_b = (unsigned short*)alloc(2ull * N_NODES * 384);
  unsigned short* wb_m1  = (unsigned short*)alloc(2ull * S0);
  unsigned short* wb_m2  = (unsigned short*)alloc(2ull * S1);   // col-permuted
  unsigned short* wb_vw  = (unsigned short*)alloc(2ull * S2);
  unsigned short* wb_u1  = (unsigned short*)alloc(2ull * S3);
  unsigned short* wb_u2  = (unsigned short*)alloc(2ull * S4);
  unsigned short* wb_fwX = (unsigned short*)alloc(2ull * S5);   // interleaved
  unsigned short* wb_ro  = (unsigned short*)alloc(2ull * S6);

  if (wsb == (char*)d_ws && o > ws_size) return;

  hipMemsetAsync(deg, 0, 4ull * N_NODES, stream);
  hipMemsetAsync(cursor, 0, 4ull * N_NODES, stream);

  cvt_all_kernel<<<(S_TOT + 255) / 256, 256, 0, stream>>>(
      msg_w1, msg_w2, vec_w, upd_w1, upd_w2, filt_w, ro_w1, msg_b2,
      wb_m1, wb_m2, wb_vw, wb_u1, wb_u2, wb_fwX, wb_ro, mb2p);

  hist_kernel<<<(N_EDGES + 255) / 256, 256, 0, stream>>>(edst, deg);
  scan_a<<<SCAN_NB, 256, 0, stream>>>(deg, bsum);
  scan_b<<<1, 64, 0, stream>>>(bsum, boff);
  scan_c<<<SCAN_NB, 256, 0, stream>>>(deg, boff, csr_off);
  fill_kernel<<<(N_EDGES + 255) / 256, 256, 0, stream>>>(esrc, edst, csr_off, cursor,
                                                         pos, srcs, geoms);
  init_kernel<<<(N_NODES * 384 + 255) / 256, 256, 0, stream>>>(z, embed, sA, sAb, svX);

  const int BIG = 1 << 30;
  const int GY40 = (N_NODES + 127) / 128;        // 313
  const int GY120 = (N_NODES * 3 + 127) / 128;   // 938
  for (int i = 0; i < NLAY; ++i) {
    const float* mb1 = msg_b1 + (size_t)i * 128;
    const float* mb2i = mb2p + (size_t)i * 384;   // permuted bias
    const float* fbv = filt_b + (size_t)i * 384;
    const float* ub1 = upd_b1 + (size_t)i * 128;
    const float* ub2 = upd_b2 + (size_t)i * 384;
    const unsigned short* m1 = wb_m1 + (size_t)i * 128 * 128;
    const unsigned short* m2 = wb_m2 + (size_t)i * 128 * 384;
    const unsigned short* vw = wb_vw + (size_t)i * 128 * 256;
    const unsigned short* u1 = wb_u1 + (size_t)i * 256 * 128;
    const unsigned short* u2 = wb_u2 + (size_t)i * 128 * 384;
    const unsigned int* fwX = (const unsigned int*)(wb_fwX + (size_t)i * 50 * 384);

    // hidden = relu(s @ m1 + b)  [40000,128]
    gemm_bf16<64, 128><<<dim3(2, GY40), 256, 0, stream>>>(sAb, 128, sAb, 128, BIG, m1,
                                                          128, mb1, hidden, 128,
                                                          N_NODES, 128, 1, 1);
    // sv s-half = hidden @ m2' + b'  (ldc=768 -> writes cols 0..383 of sv row)
    gemm_bf16<128, 128><<<dim3(3, GY40), 256, 0, stream>>>(hidden, 128, hidden, 128,
                                                           BIG, m2, 384, mb2i, svX,
                                                           768, N_NODES, 128, 0, 1);
    // message pass (unified sv gathers)
    msg_kernel<<<N_NODES / 4, 256, 0, stream>>>(csr_off, srcs, geoms,
                                                (const unsigned int*)svX, fwX, fbv,
                                                sA, sB, sBb, vBb);
    // V12 = vB @ vw  [120000,256]
    gemm_bf16<128, 128><<<dim3(2, GY120), 256, 0, stream>>>(vBb, 128, vBb, 128, BIG,
                                                            vw, 256, nullptr, Vbuf_b,
                                                            256, N_NODES * 3, 128,
                                                            0, 1);
    vnorm_kernel<<<(N_NODES * 32 + 255) / 256, 256, 0, stream>>>(Vbuf_b, vnb);
    // h2 = relu([sB|vnorm] @ u1 + b)  [40000,128] (split-A, K=256)
    gemm_bf16<64, 256><<<dim3(2, GY40), 256, 0, stream>>>(sBb, 128, vnb, 128, 128, u1,
                                                          128, ub1, hidden, 128,
                                                          N_NODES, 256, 1, 1);
    // u = h2 @ u2 + b            [40000,384]
    gemm_bf16<128, 128><<<dim3(3, GY40), 256, 0, stream>>>(hidden, 128, hidden, 128,
                                                           BIG, u2, 384, ub2, ubuf_b,
                                                           384, N_NODES, 128, 0, 1);
    // s = sB + a ; v(sv v-half) = vB*b + V2*c
    update_kernel<<<(N_NODES * 32 + 255) / 256, 256, 0, stream>>>(sB, vBb, ubuf_b,
                                                                  Vbuf_b, sA, sAb,
                                                                  (unsigned int*)svX);
  }

  gemm_bf16<64, 128><<<dim3(1, GY40), 256, 0, stream>>>(sAb, 128, sAb, 128, BIG, wb_ro,
                                                        64, ro_b1, ro_h, 64, N_NODES,
                                                        128, 1, 0);
  readout2_kernel<<<N_NODES / 4, 256, 0, stream>>>(ro_h, ro_w2, ybuf);
  pool_kernel<<<NGRAPH, 64, 0, stream>>>(ybuf, batch, ro_b2, (float*)d_out);
}